// Round 5
// baseline (374.879 us; speedup 1.0000x reference)
//
#include <hip/hip_runtime.h>

#define N_USERS 100000
#define M_ITEMS 50000
#define N_TOTAL (N_USERS + M_ITEMS)
#define D 64
#define NNZ 4000000
#define BATCH 4096

#define RPB 128                                   // rows per bucket (pow2)
#define BSHIFT 7
#define NBUCKETS ((N_TOTAL + RPB - 1) / RPB)      // 1172
#define BCAP 7680                                 // LDS edge capacity per bucket

#define TILE 8192                                 // edges per scatter block
#define SCAT_BLOCKS ((NNZ + TILE - 1) / TILE)     // 489
#define SCAT_THREADS 1024
#define EPT (TILE / SCAT_THREADS)                 // 8 edges per thread
#define CPB 2                                     // buckets per thread in block scan (1024*2>=1172)

#define LS_THREADS 1024
#define LS_EPT 8

#define INIT_BLOCKS 9375                          // 150000*64/4 float4s / 256
#define HIST_BLOCKS 512

typedef __attribute__((ext_vector_type(2))) float    f32x2;
typedef __attribute__((ext_vector_type(2))) int      i32x2;
typedef __attribute__((ext_vector_type(4))) unsigned u32x4;
typedef __attribute__((ext_vector_type(2))) unsigned u32x2;

// ---- nt-store shims (builtin rejects HIP_vector_type pointers) ----
__device__ __forceinline__ void nt_store_int2(int2 v, int2* p) {
    i32x2 t; t.x = v.x; t.y = v.y;
    __builtin_nontemporal_store(t, (i32x2*)p);
}
__device__ __forceinline__ void nt_store_uint4(uint4 v, uint4* p) {
    u32x4 t; t.x = v.x; t.y = v.y; t.z = v.z; t.w = v.w;
    __builtin_nontemporal_store(t, (u32x4*)p);
}
__device__ __forceinline__ void nt_store_uint2(uint2 v, uint2* p) {
    u32x2 t; t.x = v.x; t.y = v.y;
    __builtin_nontemporal_store(t, (u32x2*)p);
}

// ---- bf16 helpers (RNE) ----
__device__ __forceinline__ unsigned pack_bf16(float a, float b) {
    unsigned ua = __float_as_uint(a);
    unsigned ub = __float_as_uint(b);
    ua = (ua + 0x7FFFu + ((ua >> 16) & 1u)) >> 16;
    ub = (ub + 0x7FFFu + ((ub >> 16) & 1u)) & 0xFFFF0000u;
    return ua | ub;
}

// Unpack a bf16 pair into a packed f32 register pair (2 VALU ops).
__device__ __forceinline__ f32x2 unpack_bf16x2(unsigned p) {
    union { unsigned u[2]; f32x2 f; } r;
    r.u[0] = p << 16;
    r.u[1] = p & 0xFFFF0000u;
    return r.f;
}

// Inclusive block scan over 1024 threads: wave shfl-scan + 16 wave sums.
// 3 barriers total (vs 40 for Hillis-Steele over LDS).
__device__ __forceinline__ int block_scan_incl_1024(int v, int* wsum) {
    int lane = threadIdx.x & 63, wv = threadIdx.x >> 6;
#pragma unroll
    for (int o = 1; o < 64; o <<= 1) {
        int u = __shfl_up(v, o, 64);
        if (lane >= o) v += u;
    }
    if (lane == 63) wsum[wv] = v;
    __syncthreads();
    if (wv == 0) {
        int w = (lane < 16) ? wsum[lane] : 0;
#pragma unroll
        for (int o = 1; o < 16; o <<= 1) {
            int u = __shfl_up(w, o, 64);
            if (lane >= o) w += u;
        }
        if (lane < 16) wsum[lane] = w;
    }
    __syncthreads();
    return v + (wv ? wsum[wv - 1] : 0);
}

// ---------------- merged init_emb + bucket_hist (grid-split) ----------------
__global__ void init_hist_kernel(const float4* __restrict__ ue,
                                 const float4* __restrict__ ie,
                                 uint2* __restrict__ emb,
                                 const int* __restrict__ rows,
                                 int* __restrict__ bucketcnt) {
    __shared__ int h[NBUCKETS];
    if (blockIdx.x < INIT_BLOCKS) {
        // fp32 -> packed bf16 concat
        size_t i = (size_t)blockIdx.x * 256 + threadIdx.x;
        const size_t nu4 = (size_t)N_USERS * D / 4;
        float4 f = (i < nu4) ? ue[i] : ie[i - nu4];
        nt_store_uint2(make_uint2(pack_bf16(f.x, f.y), pack_bf16(f.z, f.w)),
                       emb + i);
        return;
    }
    // histogram part
    int bid = blockIdx.x - INIT_BLOCKS;
    for (int i = threadIdx.x; i < NBUCKETS; i += blockDim.x) h[i] = 0;
    __syncthreads();
    int stride = HIST_BLOCKS * 256;
    for (int e = bid * 256 + threadIdx.x; e < NNZ; e += stride)
        atomicAdd(&h[__builtin_nontemporal_load(rows + e) >> BSHIFT], 1);
    __syncthreads();
    for (int i = threadIdx.x; i < NBUCKETS; i += blockDim.x)
        if (h[i]) atomicAdd(&bucketcnt[i], h[i]);
}

__global__ void bucket_scan_kernel(const int* __restrict__ cnt,
                                   int* __restrict__ bucketoff,
                                   int* __restrict__ cursor) {
    __shared__ int wsum[16];
    int t = threadIdx.x;
    int i0 = t * 2, i1 = t * 2 + 1;
    int a = (i0 < NBUCKETS) ? cnt[i0] : 0;
    int b = (i1 < NBUCKETS) ? cnt[i1] : 0;
    int incl = block_scan_incl_1024(a + b, wsum);
    int excl = incl - a - b;
    if (i0 < NBUCKETS) { bucketoff[i0] = excl;     cursor[i0] = excl; }
    if (i1 < NBUCKETS) { bucketoff[i1] = excl + a; cursor[i1] = excl + a; }
    if (t == 0) bucketoff[NBUCKETS] = NNZ;
}

// Tile-aggregated scatter with LDS staging; lane-parallel coalesced stream-out.
__global__ __launch_bounds__(SCAT_THREADS)
void bucket_scatter_kernel(const int* __restrict__ rows,
                           const int* __restrict__ cols,
                           const float* __restrict__ vals,
                           int* __restrict__ cursor,
                           int2* __restrict__ bucketed) {
    __shared__ int hist[NBUCKETS];        // counts, then global base per bucket
    __shared__ int loff[NBUCKETS + 1];    // local exclusive prefix
    __shared__ int wsum[16];
    __shared__ int2 buf[TILE];            // 64 KB
    __shared__ int dst[TILE];             // 32 KB
    int t = threadIdx.x;
    size_t start = (size_t)blockIdx.x * TILE;
    int n = (int)(((size_t)NNZ - start < TILE) ? ((size_t)NNZ - start) : TILE);

    for (int i = t; i < NBUCKETS; i += SCAT_THREADS) hist[i] = 0;
    __syncthreads();
    // Phase A: histogram; atomicAdd's return IS the local rank.
    int rowv[EPT];
    int rank[EPT];
#pragma unroll
    for (int k = 0; k < EPT; ++k) {
        int i = t + k * SCAT_THREADS;
        if (i < n) {
            int r = __builtin_nontemporal_load(rows + start + i);
            rowv[k] = r;
            rank[k] = atomicAdd(&hist[r >> BSHIFT], 1);
        }
    }
    __syncthreads();
    // Phase B1: block scan hist -> loff (exclusive), hierarchical.
    {
        int base = t * CPB;
        int s = 0;
#pragma unroll
        for (int j = 0; j < CPB; ++j) {
            int idx = base + j;
            if (idx < NBUCKETS) s += hist[idx];
        }
        int excl = block_scan_incl_1024(s, wsum) - s;
#pragma unroll
        for (int j = 0; j < CPB; ++j) {
            int idx = base + j;
            if (idx < NBUCKETS) { loff[idx] = excl; excl += hist[idx]; }
        }
        if (t == 0) loff[NBUCKETS] = n;
    }
    __syncthreads();
    // Phase B2: one global reservation per touched bucket; hist becomes gbase.
    for (int i = t; i < NBUCKETS; i += SCAT_THREADS) {
        int c = loff[i + 1] - loff[i];
        hist[i] = c ? atomicAdd(&cursor[i], c) : 0;
    }
    __syncthreads();
    // Phase C: place edges bucket-sorted in LDS; record global dest per slot.
#pragma unroll
    for (int k = 0; k < EPT; ++k) {
        int i = t + k * SCAT_THREADS;
        if (i < n) {
            int r = rowv[k];
            int bkt = r >> BSHIFT;
            int slot = loff[bkt] + rank[k];
            int cv = __builtin_nontemporal_load(cols + start + i);
            float vv = __builtin_nontemporal_load(vals + start + i);
            buf[slot] = make_int2(((r & (RPB - 1)) << 18) | cv, __float_as_int(vv));
            dst[slot] = hist[bkt] + rank[k];
        }
    }
    __syncthreads();
    // Phase D: lane-parallel coalesced stream-out.
    for (int i = t; i < n; i += SCAT_THREADS)
        nt_store_int2(buf[i], bucketed + dst[i]);
}

// ---------------- shared SpMM edge-slot macro ----------------
// Gathers 16 B per lane (8 ui lanes cover the 128 B emb row); accumulate
// into packed-f32 pairs (v_pk_fma_f32). ei pre-masked: (0,0) when invalid.
#define EDGE_SLOT2(ei)                                                       \
    {                                                                        \
        uint4 p_  = *(const uint4*)(ebase + (ei).x);                         \
        f32x2 vv_ = {__int_as_float((ei).y), __int_as_float((ei).y)};        \
        a01 = __builtin_elementwise_fma(unpack_bf16x2(p_.x), vv_, a01);      \
        a23 = __builtin_elementwise_fma(unpack_bf16x2(p_.y), vv_, a23);      \
        a45 = __builtin_elementwise_fma(unpack_bf16x2(p_.z), vv_, a45);      \
        a67 = __builtin_elementwise_fma(unpack_bf16x2(p_.w), vv_, a67);      \
    }

#define ACC_BUTTERFLY()                                                      \
    _Pragma("unroll")                                                        \
    for (int o = 8; o <= 32; o <<= 1) {                                      \
        a01.x += __shfl_xor(a01.x, o, 64); a01.y += __shfl_xor(a01.y, o, 64);\
        a23.x += __shfl_xor(a23.x, o, 64); a23.y += __shfl_xor(a23.y, o, 64);\
        a45.x += __shfl_xor(a45.x, o, 64); a45.y += __shfl_xor(a45.y, o, 64);\
        a67.x += __shfl_xor(a67.x, o, 64); a67.y += __shfl_xor(a67.y, o, 64);\
    }

// ---------------- local sort + FUSED layer-1 SpMM ----------------
// Per-bucket counting sort in LDS (rank fused, payload in registers), then
// each wave computes the L1 segment-sum for 8 rows straight from the
// LDS-resident edge list (edge fetch = LDS same-address broadcast; emb
// gather identical to spmm). Kills the separate L1 kernel + 32 MB re-read.
__global__ __launch_bounds__(LS_THREADS)
void local_sort_l1_kernel(const int* __restrict__ bucketoff,
                          const int2* __restrict__ bucketed,
                          int* __restrict__ row_start,
                          int2* __restrict__ edges,
                          const char* __restrict__ emb_in,   // embA bf16 rows
                          uint4* __restrict__ emb_out) {     // embB
    __shared__ int hist[RPB];
    __shared__ int sc[RPB];
    __shared__ int2 buf[BCAP];            // 61.4 KB
    int b = blockIdx.x;
    int t = threadIdx.x;
    int s = bucketoff[b], e = bucketoff[b + 1], n = e - s;

    if (t < RPB) hist[t] = 0;
    __syncthreads();
    int rl[LS_EPT], rank[LS_EPT];
    int2 pay[LS_EPT];
#pragma unroll
    for (int k = 0; k < LS_EPT; ++k) {
        int i = t + k * LS_THREADS;
        if (i < n) {
            i32x2 ev = __builtin_nontemporal_load((const i32x2*)(bucketed + s + i));
            rl[k] = (int)((unsigned)ev.x >> 18);
            pay[k] = make_int2((ev.x & 0x3FFFF) << 7, ev.y);
            rank[k] = atomicAdd(&hist[rl[k]], 1);
        }
    }
    __syncthreads();
    // inclusive scan of hist[0..127] via 2 wave shfl-scans (2 barriers)
    if (t < RPB) {
        int lane = t & 63;
        int v = hist[t];
#pragma unroll
        for (int o = 1; o < 64; o <<= 1) {
            int u = __shfl_up(v, o, 64);
            if (lane >= o) v += u;
        }
        sc[t] = v;
    }
    __syncthreads();
    if (t >= 64 && t < RPB) sc[t] += sc[63];
    __syncthreads();
    if (t < RPB) {
        int excl = (t == 0) ? 0 : sc[t - 1];
        int gr = b * RPB + t;
        if (gr < N_TOTAL) row_start[gr] = s + excl;
    }
    if (b == 0 && t == 0) row_start[N_TOTAL] = NNZ;
    __syncthreads();
#pragma unroll
    for (int k = 0; k < LS_EPT; ++k) {
        int i = t + k * LS_THREADS;
        if (i < n) {
            int excl = (rl[k] == 0) ? 0 : sc[rl[k] - 1];
            int p = excl + rank[k];
            if (p < BCAP) buf[p] = pay[k];
            else          edges[s + p] = pay[k];
        }
    }
    __syncthreads();
    // stream sorted edges out (single-use until L2 pass -> nt)
    int m = (n < BCAP) ? n : BCAP;
    for (int i = t; i < m; i += LS_THREADS)
        nt_store_int2(buf[i], edges + s + i);

    // ---- fused layer-1 SpMM: wave wv handles local rows 8*wv .. 8*wv+7 ----
    int wv = t >> 6, lane = t & 63;
    int oct = lane >> 3, ui = lane & 7;
    const char* ebase = emb_in + (ui << 4);
#define LEDGE(j_) (((j_) < nn) ? (((rs + (j_)) < BCAP) ? buf[rs + (j_)]      \
                                 : edges[s + rs + (j_)]) : make_int2(0, 0))
    for (int rr = 0; rr < 8; ++rr) {
        int r = wv * 8 + rr;
        int gr = b * RPB + r;
        if (gr >= N_TOTAL) break;  // uniform within wave
        int rs = (r == 0) ? 0 : sc[r - 1];
        int nn = sc[r] - rs;
        f32x2 a01 = {0.f, 0.f}, a23 = {0.f, 0.f};
        f32x2 a45 = {0.f, 0.f}, a67 = {0.f, 0.f};
        int tmax = (nn + 7) >> 3;
        int tt = 0;
        for (; tt + 4 <= tmax; tt += 4) {
            int j0 = (tt << 3) + oct;
            int2 e0 = LEDGE(j0), e1 = LEDGE(j0 + 8);
            int2 e2 = LEDGE(j0 + 16), e3 = LEDGE(j0 + 24);
            EDGE_SLOT2(e0); EDGE_SLOT2(e1); EDGE_SLOT2(e2); EDGE_SLOT2(e3);
        }
        for (; tt < tmax; ++tt) {
            int2 e0 = LEDGE((tt << 3) + oct);
            EDGE_SLOT2(e0);
        }
        ACC_BUTTERFLY();
        if (oct == 0)
            nt_store_uint4(
                make_uint4(pack_bf16(a01.x, a01.y), pack_bf16(a23.x, a23.y),
                           pack_bf16(a45.x, a45.y), pack_bf16(a67.x, a67.y)),
                emb_out + (size_t)gr * 8 + ui);
    }
#undef LEDGE
}

// ---------------- bf16 CSR SpMM (layer 2), oct-split, shuffle-free --------
// One wave per row; edge (col,val) fetched by same-address loads across the
// oct's 8 lanes (L1 broadcast; KEEP cached — nt cost +4.5us/dispatch, r2).
#define SPMM_BODY(row_s, row_e)                                              \
    int n = (row_e) - (row_s);                                               \
    const int2* ep = edges + (row_s) + oct;                                  \
    f32x2 a01 = {0.f, 0.f}, a23 = {0.f, 0.f};                                \
    f32x2 a45 = {0.f, 0.f}, a67 = {0.f, 0.f};                                \
    int tmax = (n + 7) >> 3;                                                 \
    int t = 0;                                                               \
    for (; t + 4 <= tmax; t += 4) {                                          \
        int j0 = (t << 3) + oct;                                             \
        int2 e0 = ep[0], e1 = ep[8], e2 = ep[16], e3 = ep[24];               \
        ep += 32;                                                            \
        if (j0      >= n) e0 = make_int2(0, 0);                              \
        if (j0 + 8  >= n) e1 = make_int2(0, 0);                              \
        if (j0 + 16 >= n) e2 = make_int2(0, 0);                              \
        if (j0 + 24 >= n) e3 = make_int2(0, 0);                              \
        EDGE_SLOT2(e0); EDGE_SLOT2(e1); EDGE_SLOT2(e2); EDGE_SLOT2(e3);      \
    }                                                                        \
    for (; t < tmax; ++t) {                                                  \
        int j0 = (t << 3) + oct;                                             \
        int2 e0 = ep[0];                                                     \
        ep += 8;                                                             \
        if (j0 >= n) e0 = make_int2(0, 0);                                   \
        EDGE_SLOT2(e0);                                                      \
    }                                                                        \
    ACC_BUTTERFLY();

__global__ void spmm_csr_kernel(const int* __restrict__ row_start,
                                const int2* __restrict__ edges,   // x = col*128
                                const char* __restrict__ emb_in,  // bf16 rows
                                uint4* __restrict__ emb_out) {
    int wave = (blockIdx.x * blockDim.x + threadIdx.x) >> 6;
    int lane = threadIdx.x & 63;
    if (wave >= N_TOTAL) return;
    int oct = lane >> 3;
    int ui  = lane & 7;
    const char* ebase = emb_in + (ui << 4);
    int s = row_start[wave];
    int e = row_start[wave + 1];
    SPMM_BODY(s, e);
    if (oct == 0)
        nt_store_uint4(
            make_uint4(pack_bf16(a01.x, a01.y), pack_bf16(a23.x, a23.y),
                       pack_bf16(a45.x, a45.y), pack_bf16(a67.x, a67.y)),
            emb_out + (size_t)wave * 8 + ui);
}

// ---------------- fused tail: init + L1 + L2 + L3 + dot, one wave/sample ----
__global__ void finalize_kernel(const int* __restrict__ users,
                                const int* __restrict__ items,
                                const float* __restrict__ ue,
                                const float* __restrict__ ie,
                                const int* __restrict__ row_start,
                                const int2* __restrict__ edges,
                                const char* __restrict__ embB,   // L1 output
                                const char* __restrict__ embA,   // L2 output
                                float* __restrict__ out) {
    int wave = (blockIdx.x * blockDim.x + threadIdx.x) >> 6;
    int lane = threadIdx.x & 63;
    if (wave >= BATCH) return;
    int oct = lane >> 3;
    int ui  = lane & 7;
    const char* ebase = embA + (ui << 4);   // layer-3 gathers read embA

    int ru = users[wave];
    int ri = N_USERS + items[wave];

    f32x2 u01, u23, u45, u67, i01, i23, i45, i67;
    {
        SPMM_BODY(row_start[ru], row_start[ru + 1]);
        u01 = a01; u23 = a23; u45 = a45; u67 = a67;
    }
    {
        SPMM_BODY(row_start[ri], row_start[ri + 1]);
        i01 = a01; i23 = a23; i45 = a45; i67 = a67;
    }

    // add init (fp32) + embB + embA rows for this lane's 8 dims
    {
        const float4* up = (const float4*)(ue + (size_t)ru * D + 8 * ui);
        float4 f0 = up[0], f1 = up[1];
        u01 += (f32x2){f0.x, f0.y}; u23 += (f32x2){f0.z, f0.w};
        u45 += (f32x2){f1.x, f1.y}; u67 += (f32x2){f1.z, f1.w};
        uint4 pb = *(const uint4*)(embB + (size_t)ru * 128 + (ui << 4));
        uint4 pa = *(const uint4*)(embA + (size_t)ru * 128 + (ui << 4));
        u01 += unpack_bf16x2(pb.x) + unpack_bf16x2(pa.x);
        u23 += unpack_bf16x2(pb.y) + unpack_bf16x2(pa.y);
        u45 += unpack_bf16x2(pb.z) + unpack_bf16x2(pa.z);
        u67 += unpack_bf16x2(pb.w) + unpack_bf16x2(pa.w);
    }
    {
        const float4* ip = (const float4*)(ie + (size_t)items[wave] * D + 8 * ui);
        float4 f0 = ip[0], f1 = ip[1];
        i01 += (f32x2){f0.x, f0.y}; i23 += (f32x2){f0.z, f0.w};
        i45 += (f32x2){f1.x, f1.y}; i67 += (f32x2){f1.z, f1.w};
        uint4 pb = *(const uint4*)(embB + (size_t)ri * 128 + (ui << 4));
        uint4 pa = *(const uint4*)(embA + (size_t)ri * 128 + (ui << 4));
        i01 += unpack_bf16x2(pb.x) + unpack_bf16x2(pa.x);
        i23 += unpack_bf16x2(pb.y) + unpack_bf16x2(pa.y);
        i45 += unpack_bf16x2(pb.z) + unpack_bf16x2(pa.z);
        i67 += unpack_bf16x2(pb.w) + unpack_bf16x2(pa.w);
    }

    // dot over this lane's 8 dims
    f32x2 d = u01 * i01;
    d = __builtin_elementwise_fma(u23, i23, d);
    d = __builtin_elementwise_fma(u45, i45, d);
    d = __builtin_elementwise_fma(u67, i67, d);
    float p = d.x + d.y;
    // sum across the 8 ui lanes of each oct (octs are redundant copies)
#pragma unroll
    for (int o = 1; o <= 4; o <<= 1) p += __shfl_xor(p, o, 64);
    if (lane == 0) out[wave] = p * (1.0f / 16.0f);
}

// ---------------- launch ----------------

extern "C" void kernel_launch(void* const* d_in, const int* in_sizes, int n_in,
                              void* d_out, int out_size, void* d_ws, size_t ws_size,
                              hipStream_t stream) {
    const int*   users = (const int*)d_in[0];
    const int*   items = (const int*)d_in[1];
    const float* ue    = (const float*)d_in[2];
    const float* ie    = (const float*)d_in[3];
    const int*   rows  = (const int*)d_in[4];
    const int*   cols  = (const int*)d_in[5];
    const float* vals  = (const float*)d_in[6];
    float*       out   = (float*)d_out;

    char* ws = (char*)d_ws;
    size_t off = 0;
    auto alloc = [&](size_t bytes) {
        void* p = ws + off;
        off += (bytes + 255) & ~(size_t)255;
        return p;
    };
    const size_t NBH = (size_t)N_TOTAL * D * sizeof(unsigned short);  // 19.2 MB bf16
    char*  embA      = (char*)alloc(NBH);
    char*  embB      = (char*)alloc(NBH);
    int*   row_start = (int*)alloc(((size_t)N_TOTAL + 1) * sizeof(int));
    int*   bucketcnt = (int*)alloc((size_t)NBUCKETS * sizeof(int));
    int*   bucketoff = (int*)alloc(((size_t)NBUCKETS + 1) * sizeof(int));
    int*   cursor    = (int*)alloc((size_t)NBUCKETS * sizeof(int));
    int2*  edges     = (int2*)alloc((size_t)NNZ * sizeof(int2) + 256);  // +slack: tail overread
    int2*  bucketed  = (int2*)alloc((size_t)NNZ * sizeof(int2));

    // init (fp32->bf16 concat) + bucket histogram, one grid-split launch
    hipMemsetAsync(bucketcnt, 0, (size_t)NBUCKETS * sizeof(int), stream);
    init_hist_kernel<<<INIT_BLOCKS + HIST_BLOCKS, 256, 0, stream>>>(
        (const float4*)ue, (const float4*)ie, (uint2*)embA, rows, bucketcnt);
    bucket_scan_kernel<<<1, 1024, 0, stream>>>(bucketcnt, bucketoff, cursor);
    bucket_scatter_kernel<<<SCAT_BLOCKS, SCAT_THREADS, 0, stream>>>(
        rows, cols, vals, cursor, bucketed);

    // local sort + fused layer 1: embA -> embB, edges materialized
    local_sort_l1_kernel<<<NBUCKETS, LS_THREADS, 0, stream>>>(
        bucketoff, bucketed, row_start, edges, embA, (uint4*)embB);

    // Layer 2: embB -> embA
    spmm_csr_kernel<<<(N_TOTAL * 64 + 255) / 256, 256, 0, stream>>>(
        row_start, edges, embB, (uint4*)embA);

    // Fused tail: init + embB + embA + layer3 + dot -> out
    finalize_kernel<<<(BATCH * 64 + 255) / 256, 256, 0, stream>>>(
        users, items, ue, ie, row_start, edges, embB, embA, out);
}

// Round 6
// 345.382 us; speedup vs baseline: 1.0854x; 1.0854x over previous
//
#include <hip/hip_runtime.h>

#define N_USERS 100000
#define M_ITEMS 50000
#define N_TOTAL (N_USERS + M_ITEMS)
#define D 64
#define NNZ 4000000
#define BATCH 4096

#define RPB 128                                   // rows per bucket (pow2)
#define BSHIFT 7
#define NBUCKETS ((N_TOTAL + RPB - 1) / RPB)      // 1172
#define BCAP 7680                                 // LDS edge capacity per bucket

#define TILE 4096                                 // edges per scatter block
#define SCAT_BLOCKS ((NNZ + TILE - 1) / TILE)     // 977
#define SCAT_THREADS 1024
#define EPT (TILE / SCAT_THREADS)                 // 4 edges per thread
#define CPB 2                                     // buckets per thread in block scan (1024*2>=1172)

#define LS_THREADS 1024
#define LS_EPT 8

#define INIT_BLOCKS 9375                          // 150000*64/4 float4s / 256
#define HIST_BLOCKS 512

typedef __attribute__((ext_vector_type(2))) float    f32x2;
typedef __attribute__((ext_vector_type(2))) int      i32x2;

// ---- bf16 helpers (RNE) ----
__device__ __forceinline__ unsigned pack_bf16(float a, float b) {
    unsigned ua = __float_as_uint(a);
    unsigned ub = __float_as_uint(b);
    ua = (ua + 0x7FFFu + ((ua >> 16) & 1u)) >> 16;
    ub = (ub + 0x7FFFu + ((ub >> 16) & 1u)) & 0xFFFF0000u;
    return ua | ub;
}

// Unpack a bf16 pair into a packed f32 register pair (2 VALU ops).
__device__ __forceinline__ f32x2 unpack_bf16x2(unsigned p) {
    union { unsigned u[2]; f32x2 f; } r;
    r.u[0] = p << 16;
    r.u[1] = p & 0xFFFF0000u;
    return r.f;
}

// Inclusive block scan over 1024 threads: wave shfl-scan + 16 wave sums.
// 3 barriers total (vs 40 for Hillis-Steele over LDS).
__device__ __forceinline__ int block_scan_incl_1024(int v, int* wsum) {
    int lane = threadIdx.x & 63, wv = threadIdx.x >> 6;
#pragma unroll
    for (int o = 1; o < 64; o <<= 1) {
        int u = __shfl_up(v, o, 64);
        if (lane >= o) v += u;
    }
    if (lane == 63) wsum[wv] = v;
    __syncthreads();
    if (wv == 0) {
        int w = (lane < 16) ? wsum[lane] : 0;
#pragma unroll
        for (int o = 1; o < 16; o <<= 1) {
            int u = __shfl_up(w, o, 64);
            if (lane >= o) w += u;
        }
        if (lane < 16) wsum[lane] = w;
    }
    __syncthreads();
    return v + (wv ? wsum[wv - 1] : 0);
}

// ---------------- merged init_emb + bucket_hist (grid-split) ----------------
__global__ void init_hist_kernel(const float4* __restrict__ ue,
                                 const float4* __restrict__ ie,
                                 uint2* __restrict__ emb,
                                 const int* __restrict__ rows,
                                 int* __restrict__ bucketcnt) {
    __shared__ int h[NBUCKETS];
    if (blockIdx.x < INIT_BLOCKS) {
        // fp32 -> packed bf16 concat (plain store: embA is gathered next)
        size_t i = (size_t)blockIdx.x * 256 + threadIdx.x;
        const size_t nu4 = (size_t)N_USERS * D / 4;
        float4 f = (i < nu4) ? ue[i] : ie[i - nu4];
        emb[i] = make_uint2(pack_bf16(f.x, f.y), pack_bf16(f.z, f.w));
        return;
    }
    // histogram part
    int bid = blockIdx.x - INIT_BLOCKS;
    for (int i = threadIdx.x; i < NBUCKETS; i += blockDim.x) h[i] = 0;
    __syncthreads();
    int stride = HIST_BLOCKS * 256;
    for (int e = bid * 256 + threadIdx.x; e < NNZ; e += stride)
        atomicAdd(&h[__builtin_nontemporal_load(rows + e) >> BSHIFT], 1);
    __syncthreads();
    for (int i = threadIdx.x; i < NBUCKETS; i += blockDim.x)
        if (h[i]) atomicAdd(&bucketcnt[i], h[i]);
}

__global__ void bucket_scan_kernel(const int* __restrict__ cnt,
                                   int* __restrict__ bucketoff,
                                   int* __restrict__ cursor) {
    __shared__ int wsum[16];
    int t = threadIdx.x;
    int i0 = t * 2, i1 = t * 2 + 1;
    int a = (i0 < NBUCKETS) ? cnt[i0] : 0;
    int b = (i1 < NBUCKETS) ? cnt[i1] : 0;
    int incl = block_scan_incl_1024(a + b, wsum);
    int excl = incl - a - b;
    if (i0 < NBUCKETS) { bucketoff[i0] = excl;     cursor[i0] = excl; }
    if (i1 < NBUCKETS) { bucketoff[i1] = excl + a; cursor[i1] = excl + a; }
    if (t == 0) bucketoff[NBUCKETS] = NNZ;
}

// Tile-aggregated scatter with LDS staging; lane-parallel coalesced stream-out.
// TILE=4096 -> ~59 KB LDS -> 2 blocks/CU (was 1 at TILE=8192).
__global__ __launch_bounds__(SCAT_THREADS)
void bucket_scatter_kernel(const int* __restrict__ rows,
                           const int* __restrict__ cols,
                           const float* __restrict__ vals,
                           int* __restrict__ cursor,
                           int2* __restrict__ bucketed) {
    __shared__ int hist[NBUCKETS];        // counts, then global base per bucket
    __shared__ int loff[NBUCKETS + 1];    // local exclusive prefix
    __shared__ int wsum[16];
    __shared__ int2 buf[TILE];            // 32 KB
    __shared__ int dst[TILE];             // 16 KB
    int t = threadIdx.x;
    size_t start = (size_t)blockIdx.x * TILE;
    int n = (int)(((size_t)NNZ - start < TILE) ? ((size_t)NNZ - start) : TILE);

    for (int i = t; i < NBUCKETS; i += SCAT_THREADS) hist[i] = 0;
    __syncthreads();
    // Phase A: histogram; atomicAdd's return IS the local rank.
    int rowv[EPT];
    int rank[EPT];
#pragma unroll
    for (int k = 0; k < EPT; ++k) {
        int i = t + k * SCAT_THREADS;
        if (i < n) {
            int r = __builtin_nontemporal_load(rows + start + i);
            rowv[k] = r;
            rank[k] = atomicAdd(&hist[r >> BSHIFT], 1);
        }
    }
    __syncthreads();
    // Phase B1: block scan hist -> loff (exclusive), hierarchical.
    {
        int base = t * CPB;
        int s = 0;
#pragma unroll
        for (int j = 0; j < CPB; ++j) {
            int idx = base + j;
            if (idx < NBUCKETS) s += hist[idx];
        }
        int excl = block_scan_incl_1024(s, wsum) - s;
#pragma unroll
        for (int j = 0; j < CPB; ++j) {
            int idx = base + j;
            if (idx < NBUCKETS) { loff[idx] = excl; excl += hist[idx]; }
        }
        if (t == 0) loff[NBUCKETS] = n;
    }
    __syncthreads();
    // Phase B2: one global reservation per touched bucket; hist becomes gbase.
    for (int i = t; i < NBUCKETS; i += SCAT_THREADS) {
        int c = loff[i + 1] - loff[i];
        hist[i] = c ? atomicAdd(&cursor[i], c) : 0;
    }
    __syncthreads();
    // Phase C: place edges bucket-sorted in LDS; record global dest per slot.
#pragma unroll
    for (int k = 0; k < EPT; ++k) {
        int i = t + k * SCAT_THREADS;
        if (i < n) {
            int r = rowv[k];
            int bkt = r >> BSHIFT;
            int slot = loff[bkt] + rank[k];
            int cv = __builtin_nontemporal_load(cols + start + i);
            float vv = __builtin_nontemporal_load(vals + start + i);
            buf[slot] = make_int2(((r & (RPB - 1)) << 18) | cv, __float_as_int(vv));
            dst[slot] = hist[bkt] + rank[k];
        }
    }
    __syncthreads();
    // Phase D: lane-parallel coalesced stream-out (plain: read once next kernel).
    for (int i = t; i < n; i += SCAT_THREADS)
        bucketed[dst[i]] = buf[i];
}

// Per-bucket counting sort in LDS (rank fused, payload held in registers).
// Output edge format: x = col byte offset (col*128), y = f32 val.
__global__ __launch_bounds__(LS_THREADS)
void local_sort_kernel(const int* __restrict__ bucketoff,
                       const int2* __restrict__ bucketed,
                       int* __restrict__ row_start,
                       int2* __restrict__ edges) {
    __shared__ int hist[RPB];
    __shared__ int sc[RPB];
    __shared__ int2 buf[BCAP];            // 61.4 KB
    int b = blockIdx.x;
    int t = threadIdx.x;
    int s = bucketoff[b], e = bucketoff[b + 1], n = e - s;

    if (t < RPB) hist[t] = 0;
    __syncthreads();
    int rl[LS_EPT], rank[LS_EPT];
    int2 pay[LS_EPT];
#pragma unroll
    for (int k = 0; k < LS_EPT; ++k) {
        int i = t + k * LS_THREADS;
        if (i < n) {
            i32x2 ev = __builtin_nontemporal_load((const i32x2*)(bucketed + s + i));
            rl[k] = (int)((unsigned)ev.x >> 18);
            pay[k] = make_int2((ev.x & 0x3FFFF) << 7, ev.y);
            rank[k] = atomicAdd(&hist[rl[k]], 1);
        }
    }
    __syncthreads();
    // inclusive scan of hist[0..127] via 2 wave shfl-scans (2 barriers)
    if (t < RPB) {
        int lane = t & 63;
        int v = hist[t];
#pragma unroll
        for (int o = 1; o < 64; o <<= 1) {
            int u = __shfl_up(v, o, 64);
            if (lane >= o) v += u;
        }
        sc[t] = v;
    }
    __syncthreads();
    if (t >= 64 && t < RPB) sc[t] += sc[63];
    __syncthreads();
    if (t < RPB) {
        int excl = (t == 0) ? 0 : sc[t - 1];
        int gr = b * RPB + t;
        if (gr < N_TOTAL) row_start[gr] = s + excl;
    }
    if (b == 0 && t == 0) row_start[N_TOTAL] = NNZ;
    __syncthreads();
#pragma unroll
    for (int k = 0; k < LS_EPT; ++k) {
        int i = t + k * LS_THREADS;
        if (i < n) {
            int excl = (rl[k] == 0) ? 0 : sc[rl[k] - 1];
            int p = excl + rank[k];
            if (p < BCAP) buf[p] = pay[k];
            else          edges[s + p] = pay[k];
        }
    }
    __syncthreads();
    int m = (n < BCAP) ? n : BCAP;
    for (int i = t; i < m; i += LS_THREADS) edges[s + i] = buf[i];
}

// ---------------- shared SpMM edge-slot macro ----------------
// Gathers 16 B per lane (8 ui lanes cover the 128 B emb row); accumulate
// into packed-f32 pairs (v_pk_fma_f32). ei pre-masked: (0,0) when invalid.
#define EDGE_SLOT2(ei)                                                       \
    {                                                                        \
        uint4 p_  = *(const uint4*)(ebase + (ei).x);                         \
        f32x2 vv_ = {__int_as_float((ei).y), __int_as_float((ei).y)};        \
        a01 = __builtin_elementwise_fma(unpack_bf16x2(p_.x), vv_, a01);      \
        a23 = __builtin_elementwise_fma(unpack_bf16x2(p_.y), vv_, a23);      \
        a45 = __builtin_elementwise_fma(unpack_bf16x2(p_.z), vv_, a45);      \
        a67 = __builtin_elementwise_fma(unpack_bf16x2(p_.w), vv_, a67);      \
    }

#define ACC_BUTTERFLY()                                                      \
    _Pragma("unroll")                                                        \
    for (int o = 8; o <= 32; o <<= 1) {                                      \
        a01.x += __shfl_xor(a01.x, o, 64); a01.y += __shfl_xor(a01.y, o, 64);\
        a23.x += __shfl_xor(a23.x, o, 64); a23.y += __shfl_xor(a23.y, o, 64);\
        a45.x += __shfl_xor(a45.x, o, 64); a45.y += __shfl_xor(a45.y, o, 64);\
        a67.x += __shfl_xor(a67.x, o, 64); a67.y += __shfl_xor(a67.y, o, 64);\
    }

// ---------------- bf16 CSR SpMM, oct-split, shuffle-free ----------------
// One wave per row; edge (col,val) fetched by same-address loads across the
// oct's 8 lanes (L1 broadcast; KEEP cached — nt cost +4.5us/dispatch, r2).
#define SPMM_BODY(row_s, row_e)                                              \
    int n = (row_e) - (row_s);                                               \
    const int2* ep = edges + (row_s) + oct;                                  \
    f32x2 a01 = {0.f, 0.f}, a23 = {0.f, 0.f};                                \
    f32x2 a45 = {0.f, 0.f}, a67 = {0.f, 0.f};                                \
    int tmax = (n + 7) >> 3;                                                 \
    int t = 0;                                                               \
    for (; t + 4 <= tmax; t += 4) {                                          \
        int j0 = (t << 3) + oct;                                             \
        int2 e0 = ep[0], e1 = ep[8], e2 = ep[16], e3 = ep[24];               \
        ep += 32;                                                            \
        if (j0      >= n) e0 = make_int2(0, 0);                              \
        if (j0 + 8  >= n) e1 = make_int2(0, 0);                              \
        if (j0 + 16 >= n) e2 = make_int2(0, 0);                              \
        if (j0 + 24 >= n) e3 = make_int2(0, 0);                              \
        EDGE_SLOT2(e0); EDGE_SLOT2(e1); EDGE_SLOT2(e2); EDGE_SLOT2(e3);      \
    }                                                                        \
    for (; t < tmax; ++t) {                                                  \
        int j0 = (t << 3) + oct;                                             \
        int2 e0 = ep[0];                                                     \
        ep += 8;                                                             \
        if (j0 >= n) e0 = make_int2(0, 0);                                   \
        EDGE_SLOT2(e0);                                                      \
    }                                                                        \
    ACC_BUTTERFLY();

__global__ void spmm_csr_kernel(const int* __restrict__ row_start,
                                const int2* __restrict__ edges,   // x = col*128
                                const char* __restrict__ emb_in,  // bf16 rows
                                uint4* __restrict__ emb_out) {
    int wave = (blockIdx.x * blockDim.x + threadIdx.x) >> 6;
    int lane = threadIdx.x & 63;
    if (wave >= N_TOTAL) return;
    int oct = lane >> 3;
    int ui  = lane & 7;
    const char* ebase = emb_in + (ui << 4);
    int s = row_start[wave];
    int e = row_start[wave + 1];
    SPMM_BODY(s, e);
    if (oct == 0)
        emb_out[(size_t)wave * 8 + ui] =
            make_uint4(pack_bf16(a01.x, a01.y), pack_bf16(a23.x, a23.y),
                       pack_bf16(a45.x, a45.y), pack_bf16(a67.x, a67.y));
}

// ---------------- fused tail: init + L1 + L2 + L3 + dot, one wave/sample ----
__global__ void finalize_kernel(const int* __restrict__ users,
                                const int* __restrict__ items,
                                const float* __restrict__ ue,
                                const float* __restrict__ ie,
                                const int* __restrict__ row_start,
                                const int2* __restrict__ edges,
                                const char* __restrict__ embB,   // L1 output
                                const char* __restrict__ embA,   // L2 output
                                float* __restrict__ out) {
    int wave = (blockIdx.x * blockDim.x + threadIdx.x) >> 6;
    int lane = threadIdx.x & 63;
    if (wave >= BATCH) return;
    int oct = lane >> 3;
    int ui  = lane & 7;
    const char* ebase = embA + (ui << 4);   // layer-3 gathers read embA

    int ru = users[wave];
    int ri = N_USERS + items[wave];

    f32x2 u01, u23, u45, u67, i01, i23, i45, i67;
    {
        SPMM_BODY(row_start[ru], row_start[ru + 1]);
        u01 = a01; u23 = a23; u45 = a45; u67 = a67;
    }
    {
        SPMM_BODY(row_start[ri], row_start[ri + 1]);
        i01 = a01; i23 = a23; i45 = a45; i67 = a67;
    }

    // add init (fp32) + embB + embA rows for this lane's 8 dims
    {
        const float4* up = (const float4*)(ue + (size_t)ru * D + 8 * ui);
        float4 f0 = up[0], f1 = up[1];
        u01 += (f32x2){f0.x, f0.y}; u23 += (f32x2){f0.z, f0.w};
        u45 += (f32x2){f1.x, f1.y}; u67 += (f32x2){f1.z, f1.w};
        uint4 pb = *(const uint4*)(embB + (size_t)ru * 128 + (ui << 4));
        uint4 pa = *(const uint4*)(embA + (size_t)ru * 128 + (ui << 4));
        u01 += unpack_bf16x2(pb.x) + unpack_bf16x2(pa.x);
        u23 += unpack_bf16x2(pb.y) + unpack_bf16x2(pa.y);
        u45 += unpack_bf16x2(pb.z) + unpack_bf16x2(pa.z);
        u67 += unpack_bf16x2(pb.w) + unpack_bf16x2(pa.w);
    }
    {
        const float4* ip = (const float4*)(ie + (size_t)items[wave] * D + 8 * ui);
        float4 f0 = ip[0], f1 = ip[1];
        i01 += (f32x2){f0.x, f0.y}; i23 += (f32x2){f0.z, f0.w};
        i45 += (f32x2){f1.x, f1.y}; i67 += (f32x2){f1.z, f1.w};
        uint4 pb = *(const uint4*)(embB + (size_t)ri * 128 + (ui << 4));
        uint4 pa = *(const uint4*)(embA + (size_t)ri * 128 + (ui << 4));
        i01 += unpack_bf16x2(pb.x) + unpack_bf16x2(pa.x);
        i23 += unpack_bf16x2(pb.y) + unpack_bf16x2(pa.y);
        i45 += unpack_bf16x2(pb.z) + unpack_bf16x2(pa.z);
        i67 += unpack_bf16x2(pb.w) + unpack_bf16x2(pa.w);
    }

    // dot over this lane's 8 dims
    f32x2 d = u01 * i01;
    d = __builtin_elementwise_fma(u23, i23, d);
    d = __builtin_elementwise_fma(u45, i45, d);
    d = __builtin_elementwise_fma(u67, i67, d);
    float p = d.x + d.y;
    // sum across the 8 ui lanes of each oct (octs are redundant copies)
#pragma unroll
    for (int o = 1; o <= 4; o <<= 1) p += __shfl_xor(p, o, 64);
    if (lane == 0) out[wave] = p * (1.0f / 16.0f);
}

// ---------------- launch ----------------

extern "C" void kernel_launch(void* const* d_in, const int* in_sizes, int n_in,
                              void* d_out, int out_size, void* d_ws, size_t ws_size,
                              hipStream_t stream) {
    const int*   users = (const int*)d_in[0];
    const int*   items = (const int*)d_in[1];
    const float* ue    = (const float*)d_in[2];
    const float* ie    = (const float*)d_in[3];
    const int*   rows  = (const int*)d_in[4];
    const int*   cols  = (const int*)d_in[5];
    const float* vals  = (const float*)d_in[6];
    float*       out   = (float*)d_out;

    char* ws = (char*)d_ws;
    size_t off = 0;
    auto alloc = [&](size_t bytes) {
        void* p = ws + off;
        off += (bytes + 255) & ~(size_t)255;
        return p;
    };
    const size_t NBH = (size_t)N_TOTAL * D * sizeof(unsigned short);  // 19.2 MB bf16
    char*  embA      = (char*)alloc(NBH);
    char*  embB      = (char*)alloc(NBH);
    int*   row_start = (int*)alloc(((size_t)N_TOTAL + 1) * sizeof(int));
    int*   bucketcnt = (int*)alloc((size_t)NBUCKETS * sizeof(int));
    int*   bucketoff = (int*)alloc(((size_t)NBUCKETS + 1) * sizeof(int));
    int*   cursor    = (int*)alloc((size_t)NBUCKETS * sizeof(int));
    int2*  edges     = (int2*)alloc((size_t)NNZ * sizeof(int2) + 256);  // +slack: tail overread
    int2*  bucketed  = (int2*)alloc((size_t)NNZ * sizeof(int2));

    // init (fp32->bf16 concat) + bucket histogram, one grid-split launch
    hipMemsetAsync(bucketcnt, 0, (size_t)NBUCKETS * sizeof(int), stream);
    init_hist_kernel<<<INIT_BLOCKS + HIST_BLOCKS, 256, 0, stream>>>(
        (const float4*)ue, (const float4*)ie, (uint2*)embA, rows, bucketcnt);
    bucket_scan_kernel<<<1, 1024, 0, stream>>>(bucketcnt, bucketoff, cursor);
    bucket_scatter_kernel<<<SCAT_BLOCKS, SCAT_THREADS, 0, stream>>>(
        rows, cols, vals, cursor, bucketed);
    local_sort_kernel<<<NBUCKETS, LS_THREADS, 0, stream>>>(
        bucketoff, bucketed, row_start, edges);

    // Layer 1: embA -> embB
    spmm_csr_kernel<<<(N_TOTAL * 64 + 255) / 256, 256, 0, stream>>>(
        row_start, edges, embA, (uint4*)embB);

    // Layer 2: embB -> embA
    spmm_csr_kernel<<<(N_TOTAL * 64 + 255) / 256, 256, 0, stream>>>(
        row_start, edges, embB, (uint4*)embA);

    // Fused tail: init + embB + embA + layer3 + dot -> out
    finalize_kernel<<<(BATCH * 64 + 255) / 256, 256, 0, stream>>>(
        users, items, ue, ie, row_start, edges, embB, embA, out);
}

// Round 7
// 341.438 us; speedup vs baseline: 1.0979x; 1.0115x over previous
//
#include <hip/hip_runtime.h>

#define N_USERS 100000
#define M_ITEMS 50000
#define N_TOTAL (N_USERS + M_ITEMS)
#define D 64
#define NNZ 4000000
#define BATCH 4096

#define RPB 128                                   // rows per bucket (pow2)
#define BSHIFT 7
#define NBUCKETS ((N_TOTAL + RPB - 1) / RPB)      // 1172
#define BCAP 4352                                 // LDS edge cap (mean 3413, +16 sigma) -> 34 KB

#define TILE 4096                                 // edges per scatter block
#define SCAT_BLOCKS ((NNZ + TILE - 1) / TILE)     // 977
#define SCAT_THREADS 1024
#define EPT (TILE / SCAT_THREADS)                 // 4 edges per thread
#define CPB 2                                     // buckets per thread in block scan (1024*2>=1172)

#define LS_THREADS 1024
#define LS_EPT 8

#define INIT_BLOCKS 9375                          // 150000*64/4 float4s / 256
#define HIST_BLOCKS 512

typedef __attribute__((ext_vector_type(2))) float    f32x2;
typedef __attribute__((ext_vector_type(2))) int      i32x2;

// ---- bf16 helpers (RNE) ----
__device__ __forceinline__ unsigned pack_bf16(float a, float b) {
    unsigned ua = __float_as_uint(a);
    unsigned ub = __float_as_uint(b);
    ua = (ua + 0x7FFFu + ((ua >> 16) & 1u)) >> 16;
    ub = (ub + 0x7FFFu + ((ub >> 16) & 1u)) & 0xFFFF0000u;
    return ua | ub;
}

// Unpack a bf16 pair into a packed f32 register pair (2 VALU ops).
__device__ __forceinline__ f32x2 unpack_bf16x2(unsigned p) {
    union { unsigned u[2]; f32x2 f; } r;
    r.u[0] = p << 16;
    r.u[1] = p & 0xFFFF0000u;
    return r.f;
}

// Inclusive block scan over 1024 threads: wave shfl-scan + 16 wave sums.
__device__ __forceinline__ int block_scan_incl_1024(int v, int* wsum) {
    int lane = threadIdx.x & 63, wv = threadIdx.x >> 6;
#pragma unroll
    for (int o = 1; o < 64; o <<= 1) {
        int u = __shfl_up(v, o, 64);
        if (lane >= o) v += u;
    }
    if (lane == 63) wsum[wv] = v;
    __syncthreads();
    if (wv == 0) {
        int w = (lane < 16) ? wsum[lane] : 0;
#pragma unroll
        for (int o = 1; o < 16; o <<= 1) {
            int u = __shfl_up(w, o, 64);
            if (lane >= o) w += u;
        }
        if (lane < 16) wsum[lane] = w;
    }
    __syncthreads();
    return v + (wv ? wsum[wv - 1] : 0);
}

// ---------------- merged init_emb + bucket_hist (grid-split) ----------------
__global__ void init_hist_kernel(const float4* __restrict__ ue,
                                 const float4* __restrict__ ie,
                                 uint2* __restrict__ emb,
                                 const int* __restrict__ rows,
                                 int* __restrict__ bucketcnt) {
    __shared__ int h[NBUCKETS];
    if (blockIdx.x < INIT_BLOCKS) {
        // fp32 -> packed bf16 concat (plain store: embA is gathered next)
        size_t i = (size_t)blockIdx.x * 256 + threadIdx.x;
        const size_t nu4 = (size_t)N_USERS * D / 4;
        float4 f = (i < nu4) ? ue[i] : ie[i - nu4];
        emb[i] = make_uint2(pack_bf16(f.x, f.y), pack_bf16(f.z, f.w));
        return;
    }
    // histogram part
    int bid = blockIdx.x - INIT_BLOCKS;
    for (int i = threadIdx.x; i < NBUCKETS; i += blockDim.x) h[i] = 0;
    __syncthreads();
    int stride = HIST_BLOCKS * 256;
    for (int e = bid * 256 + threadIdx.x; e < NNZ; e += stride)
        atomicAdd(&h[__builtin_nontemporal_load(rows + e) >> BSHIFT], 1);
    __syncthreads();
    for (int i = threadIdx.x; i < NBUCKETS; i += blockDim.x)
        if (h[i]) atomicAdd(&bucketcnt[i], h[i]);
}

__global__ void bucket_scan_kernel(const int* __restrict__ cnt,
                                   int* __restrict__ bucketoff,
                                   int* __restrict__ cursor) {
    __shared__ int wsum[16];
    int t = threadIdx.x;
    int i0 = t * 2, i1 = t * 2 + 1;
    int a = (i0 < NBUCKETS) ? cnt[i0] : 0;
    int b = (i1 < NBUCKETS) ? cnt[i1] : 0;
    int incl = block_scan_incl_1024(a + b, wsum);
    int excl = incl - a - b;
    if (i0 < NBUCKETS) { bucketoff[i0] = excl;     cursor[i0] = excl; }
    if (i1 < NBUCKETS) { bucketoff[i1] = excl + a; cursor[i1] = excl + a; }
    if (t == 0) bucketoff[NBUCKETS] = NNZ;
}

// Tile-aggregated scatter with LDS staging; lane-parallel coalesced stream-out.
// TILE=4096 -> ~59 KB LDS -> 2 blocks/CU.
__global__ __launch_bounds__(SCAT_THREADS)
void bucket_scatter_kernel(const int* __restrict__ rows,
                           const int* __restrict__ cols,
                           const float* __restrict__ vals,
                           int* __restrict__ cursor,
                           int2* __restrict__ bucketed) {
    __shared__ int hist[NBUCKETS];        // counts, then global base per bucket
    __shared__ int loff[NBUCKETS + 1];    // local exclusive prefix
    __shared__ int wsum[16];
    __shared__ int2 buf[TILE];            // 32 KB
    __shared__ int dst[TILE];             // 16 KB
    int t = threadIdx.x;
    size_t start = (size_t)blockIdx.x * TILE;
    int n = (int)(((size_t)NNZ - start < TILE) ? ((size_t)NNZ - start) : TILE);

    for (int i = t; i < NBUCKETS; i += SCAT_THREADS) hist[i] = 0;
    __syncthreads();
    // Phase A: histogram; atomicAdd's return IS the local rank.
    int rowv[EPT];
    int rank[EPT];
#pragma unroll
    for (int k = 0; k < EPT; ++k) {
        int i = t + k * SCAT_THREADS;
        if (i < n) {
            int r = __builtin_nontemporal_load(rows + start + i);
            rowv[k] = r;
            rank[k] = atomicAdd(&hist[r >> BSHIFT], 1);
        }
    }
    __syncthreads();
    // Phase B1: block scan hist -> loff (exclusive), hierarchical.
    {
        int base = t * CPB;
        int s = 0;
#pragma unroll
        for (int j = 0; j < CPB; ++j) {
            int idx = base + j;
            if (idx < NBUCKETS) s += hist[idx];
        }
        int excl = block_scan_incl_1024(s, wsum) - s;
#pragma unroll
        for (int j = 0; j < CPB; ++j) {
            int idx = base + j;
            if (idx < NBUCKETS) { loff[idx] = excl; excl += hist[idx]; }
        }
        if (t == 0) loff[NBUCKETS] = n;
    }
    __syncthreads();
    // Phase B2: one global reservation per touched bucket; hist becomes gbase.
    for (int i = t; i < NBUCKETS; i += SCAT_THREADS) {
        int c = loff[i + 1] - loff[i];
        hist[i] = c ? atomicAdd(&cursor[i], c) : 0;
    }
    __syncthreads();
    // Phase C: place edges bucket-sorted in LDS; record global dest per slot.
#pragma unroll
    for (int k = 0; k < EPT; ++k) {
        int i = t + k * SCAT_THREADS;
        if (i < n) {
            int r = rowv[k];
            int bkt = r >> BSHIFT;
            int slot = loff[bkt] + rank[k];
            int cv = __builtin_nontemporal_load(cols + start + i);
            float vv = __builtin_nontemporal_load(vals + start + i);
            buf[slot] = make_int2(((r & (RPB - 1)) << 18) | cv, __float_as_int(vv));
            dst[slot] = hist[bkt] + rank[k];
        }
    }
    __syncthreads();
    // Phase D: lane-parallel coalesced stream-out (plain: read once next kernel).
    for (int i = t; i < n; i += SCAT_THREADS)
        bucketed[dst[i]] = buf[i];
}

// Per-bucket counting sort in LDS (rank fused, payload held in registers).
// BCAP=4352 -> 34 KB LDS -> 4 blocks/CU (2x occupancy vs BCAP=7680).
// Output edge format: x = col byte offset (col*128), y = f32 val.
__global__ __launch_bounds__(LS_THREADS)
void local_sort_kernel(const int* __restrict__ bucketoff,
                       const int2* __restrict__ bucketed,
                       int* __restrict__ row_start,
                       int2* __restrict__ edges) {
    __shared__ int hist[RPB];
    __shared__ int sc[RPB];
    __shared__ int2 buf[BCAP];            // 34 KB
    int b = blockIdx.x;
    int t = threadIdx.x;
    int s = bucketoff[b], e = bucketoff[b + 1], n = e - s;

    if (t < RPB) hist[t] = 0;
    __syncthreads();
    int rl[LS_EPT], rank[LS_EPT];
    int2 pay[LS_EPT];
#pragma unroll
    for (int k = 0; k < LS_EPT; ++k) {
        int i = t + k * LS_THREADS;
        if (i < n) {
            i32x2 ev = __builtin_nontemporal_load((const i32x2*)(bucketed + s + i));
            rl[k] = (int)((unsigned)ev.x >> 18);
            pay[k] = make_int2((ev.x & 0x3FFFF) << 7, ev.y);
            rank[k] = atomicAdd(&hist[rl[k]], 1);
        }
    }
    __syncthreads();
    // inclusive scan of hist[0..127] via 2 wave shfl-scans (2 barriers)
    if (t < RPB) {
        int lane = t & 63;
        int v = hist[t];
#pragma unroll
        for (int o = 1; o < 64; o <<= 1) {
            int u = __shfl_up(v, o, 64);
            if (lane >= o) v += u;
        }
        sc[t] = v;
    }
    __syncthreads();
    if (t >= 64 && t < RPB) sc[t] += sc[63];
    __syncthreads();
    if (t < RPB) {
        int excl = (t == 0) ? 0 : sc[t - 1];
        int gr = b * RPB + t;
        if (gr < N_TOTAL) row_start[gr] = s + excl;
    }
    if (b == 0 && t == 0) row_start[N_TOTAL] = NNZ;
    __syncthreads();
#pragma unroll
    for (int k = 0; k < LS_EPT; ++k) {
        int i = t + k * LS_THREADS;
        if (i < n) {
            int excl = (rl[k] == 0) ? 0 : sc[rl[k] - 1];
            int p = excl + rank[k];
            if (p < BCAP) buf[p] = pay[k];
            else          edges[s + p] = pay[k];
        }
    }
    __syncthreads();
    int m = (n < BCAP) ? n : BCAP;
    for (int i = t; i < m; i += LS_THREADS) edges[s + i] = buf[i];
}

// ---------------- bf16 CSR SpMM, oct-split, shuffle-free ----------------
// r3-EXACT body (measured 68.36 us; r6's masked variant cost +3 us).
// One wave per row. oct = lane>>3 processes edge slot j = 8t+oct; ui = lane&7
// covers dims 8ui..8ui+7 via one uint4 gather. Edge (col,val) fetched by
// same-address loads across the oct's 8 lanes (L1 broadcast; keep cached).
// Invalid slots gather col 0 (L1-resident) with val forced to 0.

#define EDGE_SLOT(ei, ji)                                                    \
    {                                                                        \
        int   c_  = (ji < n) ? ei.x : 0;                                     \
        float mv_ = (ji < n) ? __int_as_float(ei.y) : 0.0f;                  \
        uint4 p_  = *(const uint4*)(ebase + c_);                             \
        f32x2 vv_ = {mv_, mv_};                                              \
        a01 = __builtin_elementwise_fma(unpack_bf16x2(p_.x), vv_, a01);      \
        a23 = __builtin_elementwise_fma(unpack_bf16x2(p_.y), vv_, a23);      \
        a45 = __builtin_elementwise_fma(unpack_bf16x2(p_.z), vv_, a45);      \
        a67 = __builtin_elementwise_fma(unpack_bf16x2(p_.w), vv_, a67);      \
    }

#define SPMM_BODY(row_s, row_e)                                              \
    int n = (row_e) - (row_s);                                               \
    const int2* ep = edges + (row_s) + oct;                                  \
    f32x2 a01 = {0.f, 0.f}, a23 = {0.f, 0.f};                                \
    f32x2 a45 = {0.f, 0.f}, a67 = {0.f, 0.f};                                \
    int tmax = (n + 7) >> 3;                                                 \
    int t = 0;                                                               \
    for (; t + 4 <= tmax; t += 4) {                                          \
        int2 e0 = ep[0], e1 = ep[8], e2 = ep[16], e3 = ep[24];               \
        ep += 32;                                                            \
        int j0 = (t << 3) + oct;                                             \
        EDGE_SLOT(e0, j0);                                                   \
        EDGE_SLOT(e1, (j0 + 8));                                             \
        EDGE_SLOT(e2, (j0 + 16));                                            \
        EDGE_SLOT(e3, (j0 + 24));                                            \
    }                                                                        \
    if (t + 2 <= tmax) {                                                     \
        int2 e0 = ep[0], e1 = ep[8];                                         \
        ep += 16;                                                            \
        int j0 = (t << 3) + oct;                                             \
        EDGE_SLOT(e0, j0);                                                   \
        EDGE_SLOT(e1, (j0 + 8));                                             \
        t += 2;                                                              \
    }                                                                        \
    if (t < tmax) {                                                          \
        int2 e0 = ep[0];                                                     \
        int j0 = (t << 3) + oct;                                             \
        EDGE_SLOT(e0, j0);                                                   \
    }                                                                        \
    _Pragma("unroll")                                                        \
    for (int o = 8; o <= 32; o <<= 1) {                                      \
        a01.x += __shfl_xor(a01.x, o, 64); a01.y += __shfl_xor(a01.y, o, 64);\
        a23.x += __shfl_xor(a23.x, o, 64); a23.y += __shfl_xor(a23.y, o, 64);\
        a45.x += __shfl_xor(a45.x, o, 64); a45.y += __shfl_xor(a45.y, o, 64);\
        a67.x += __shfl_xor(a67.x, o, 64); a67.y += __shfl_xor(a67.y, o, 64);\
    }

__global__ void spmm_csr_kernel(const int* __restrict__ row_start,
                                const int2* __restrict__ edges,   // x = col*128
                                const char* __restrict__ emb_in,  // bf16 rows
                                uint4* __restrict__ emb_out) {
    int wave = (blockIdx.x * blockDim.x + threadIdx.x) >> 6;
    int lane = threadIdx.x & 63;
    if (wave >= N_TOTAL) return;
    int oct = lane >> 3;
    int ui  = lane & 7;
    const char* ebase = emb_in + (ui << 4);
    int s = row_start[wave];
    int e = row_start[wave + 1];
    SPMM_BODY(s, e);
    if (oct == 0)
        emb_out[(size_t)wave * 8 + ui] =
            make_uint4(pack_bf16(a01.x, a01.y), pack_bf16(a23.x, a23.y),
                       pack_bf16(a45.x, a45.y), pack_bf16(a67.x, a67.y));
}

// ---------------- fused tail: init + L1 + L2 + L3 + dot, one wave/sample ----
__global__ void finalize_kernel(const int* __restrict__ users,
                                const int* __restrict__ items,
                                const float* __restrict__ ue,
                                const float* __restrict__ ie,
                                const int* __restrict__ row_start,
                                const int2* __restrict__ edges,
                                const char* __restrict__ embB,   // L1 output
                                const char* __restrict__ embA,   // L2 output
                                float* __restrict__ out) {
    int wave = (blockIdx.x * blockDim.x + threadIdx.x) >> 6;
    int lane = threadIdx.x & 63;
    if (wave >= BATCH) return;
    int oct = lane >> 3;
    int ui  = lane & 7;
    const char* ebase = embA + (ui << 4);   // layer-3 gathers read embA

    int ru = users[wave];
    int ri = N_USERS + items[wave];

    f32x2 u01, u23, u45, u67, i01, i23, i45, i67;
    {
        SPMM_BODY(row_start[ru], row_start[ru + 1]);
        u01 = a01; u23 = a23; u45 = a45; u67 = a67;
    }
    {
        SPMM_BODY(row_start[ri], row_start[ri + 1]);
        i01 = a01; i23 = a23; i45 = a45; i67 = a67;
    }

    // add init (fp32) + embB + embA rows for this lane's 8 dims
    {
        const float4* up = (const float4*)(ue + (size_t)ru * D + 8 * ui);
        float4 f0 = up[0], f1 = up[1];
        u01 += (f32x2){f0.x, f0.y}; u23 += (f32x2){f0.z, f0.w};
        u45 += (f32x2){f1.x, f1.y}; u67 += (f32x2){f1.z, f1.w};
        uint4 pb = *(const uint4*)(embB + (size_t)ru * 128 + (ui << 4));
        uint4 pa = *(const uint4*)(embA + (size_t)ru * 128 + (ui << 4));
        u01 += unpack_bf16x2(pb.x) + unpack_bf16x2(pa.x);
        u23 += unpack_bf16x2(pb.y) + unpack_bf16x2(pa.y);
        u45 += unpack_bf16x2(pb.z) + unpack_bf16x2(pa.z);
        u67 += unpack_bf16x2(pb.w) + unpack_bf16x2(pa.w);
    }
    {
        const float4* ip = (const float4*)(ie + (size_t)items[wave] * D + 8 * ui);
        float4 f0 = ip[0], f1 = ip[1];
        i01 += (f32x2){f0.x, f0.y}; i23 += (f32x2){f0.z, f0.w};
        i45 += (f32x2){f1.x, f1.y}; i67 += (f32x2){f1.z, f1.w};
        uint4 pb = *(const uint4*)(embB + (size_t)ri * 128 + (ui << 4));
        uint4 pa = *(const uint4*)(embA + (size_t)ri * 128 + (ui << 4));
        i01 += unpack_bf16x2(pb.x) + unpack_bf16x2(pa.x);
        i23 += unpack_bf16x2(pb.y) + unpack_bf16x2(pa.y);
        i45 += unpack_bf16x2(pb.z) + unpack_bf16x2(pa.z);
        i67 += unpack_bf16x2(pb.w) + unpack_bf16x2(pa.w);
    }

    // dot over this lane's 8 dims
    f32x2 d = u01 * i01;
    d = __builtin_elementwise_fma(u23, i23, d);
    d = __builtin_elementwise_fma(u45, i45, d);
    d = __builtin_elementwise_fma(u67, i67, d);
    float p = d.x + d.y;
    // sum across the 8 ui lanes of each oct (octs are redundant copies)
#pragma unroll
    for (int o = 1; o <= 4; o <<= 1) p += __shfl_xor(p, o, 64);
    if (lane == 0) out[wave] = p * (1.0f / 16.0f);
}

// ---------------- launch ----------------

extern "C" void kernel_launch(void* const* d_in, const int* in_sizes, int n_in,
                              void* d_out, int out_size, void* d_ws, size_t ws_size,
                              hipStream_t stream) {
    const int*   users = (const int*)d_in[0];
    const int*   items = (const int*)d_in[1];
    const float* ue    = (const float*)d_in[2];
    const float* ie    = (const float*)d_in[3];
    const int*   rows  = (const int*)d_in[4];
    const int*   cols  = (const int*)d_in[5];
    const float* vals  = (const float*)d_in[6];
    float*       out   = (float*)d_out;

    char* ws = (char*)d_ws;
    size_t off = 0;
    auto alloc = [&](size_t bytes) {
        void* p = ws + off;
        off += (bytes + 255) & ~(size_t)255;
        return p;
    };
    const size_t NBH = (size_t)N_TOTAL * D * sizeof(unsigned short);  // 19.2 MB bf16
    char*  embA      = (char*)alloc(NBH);
    char*  embB      = (char*)alloc(NBH);
    int*   row_start = (int*)alloc(((size_t)N_TOTAL + 1) * sizeof(int));
    int*   bucketcnt = (int*)alloc((size_t)NBUCKETS * sizeof(int));
    int*   bucketoff = (int*)alloc(((size_t)NBUCKETS + 1) * sizeof(int));
    int*   cursor    = (int*)alloc((size_t)NBUCKETS * sizeof(int));
    int2*  edges     = (int2*)alloc((size_t)NNZ * sizeof(int2) + 256);  // +slack: tail overread
    int2*  bucketed  = (int2*)alloc((size_t)NNZ * sizeof(int2));

    // init (fp32->bf16 concat) + bucket histogram, one grid-split launch
    hipMemsetAsync(bucketcnt, 0, (size_t)NBUCKETS * sizeof(int), stream);
    init_hist_kernel<<<INIT_BLOCKS + HIST_BLOCKS, 256, 0, stream>>>(
        (const float4*)ue, (const float4*)ie, (uint2*)embA, rows, bucketcnt);
    bucket_scan_kernel<<<1, 1024, 0, stream>>>(bucketcnt, bucketoff, cursor);
    bucket_scatter_kernel<<<SCAT_BLOCKS, SCAT_THREADS, 0, stream>>>(
        rows, cols, vals, cursor, bucketed);
    local_sort_kernel<<<NBUCKETS, LS_THREADS, 0, stream>>>(
        bucketoff, bucketed, row_start, edges);

    // Layer 1: embA -> embB
    spmm_csr_kernel<<<(N_TOTAL * 64 + 255) / 256, 256, 0, stream>>>(
        row_start, edges, embA, (uint4*)embB);

    // Layer 2: embB -> embA
    spmm_csr_kernel<<<(N_TOTAL * 64 + 255) / 256, 256, 0, stream>>>(
        row_start, edges, embB, (uint4*)embA);

    // Fused tail: init + embB + embA + layer3 + dot -> out
    finalize_kernel<<<(BATCH * 64 + 255) / 256, 256, 0, stream>>>(
        users, items, ue, ie, row_start, edges, embB, embA, out);
}